// Round 6
// baseline (2120.341 us; speedup 1.0000x reference)
//
#include <hip/hip_runtime.h>
#include <math.h>

// Problem constants: T=2048, B=256, H=128, IN_DIM=1, NUM_DATA=4096
#define T_STEPS 2048
#define BATCH   256
#define HDIM    128

__device__ __forceinline__ float fast_rcp(float x) { return __builtin_amdgcn_rcpf(x); }
__device__ __forceinline__ float sigmoid_f(float x) { return fast_rcp(1.0f + __expf(-x)); }
__device__ __forceinline__ float tanh_f(float x) {
    float e = __expf(2.0f * x);
    return 1.0f - 2.0f * fast_rcp(e + 1.0f);
}

#define REP16(M) M(0) M(1) M(2) M(3) M(4) M(5) M(6) M(7) \
                 M(8) M(9) M(10) M(11) M(12) M(13) M(14) M(15)

// One block per batch element (256 blocks -> 1/CU), 512 threads = 8 waves =
// 2 waves/SIMD. Threads (2p, 2p+1) jointly own gate rows 2p and 2p+1:
// even thread covers h[0:64), odd thread h[64:128).
//
// R6 change (single variable): __launch_bounds__(512, 1) and NO
// amdgpu_waves_per_eu attr. R5 evidence (VGPR=80, VALU-issue ~1100/step =
// 512 FMA + ~512 extra) says the allocator kept the weights in AGPRs and
// paid a v_accvgpr_read per use. Physical occupancy is unchanged (one
// 8-wave block per CU); the relaxed min-waves budget removes the pressure
// that triggered AGPR spilling, so the 128 weight floats can live in arch
// VGPRs and feed v_fma directly.
//
// Carried from R3-R5 (all verified):
//  * volatile asm pins (non-volatile asm got rematerialized into the loop).
//  * h stored split with a 16-word gap -> even-lane reads (words 4i) and
//    odd-lane reads (words 80+4i) hit disjoint bank groups; R5 measured
//    SQ_LDS_BANK_CONFLICT == 0.
//  * waves 2-3 mirror the c/h update and own the y-reduction; part index
//    (tid - HDIM) >> 6 (R4's OOB bug fixed in R5).
//  * feedback fold: x_t = h_{t-1}.W_lin + b_lin  =>
//    gates_t = h_{t-1}.(W_hh + W_ih (x) W_lin)^T + (b + W_ih*b_lin),
//    t=0 corrected by subtracting wih*y_init from the bias on iteration 0.
//    absmax 0.0 in R3/R5.
__global__ __launch_bounds__(512, 1)
void lstm_seq_kernel(const int*   __restrict__ label,
                     const float* __restrict__ h0,     // (1, 4096, 128)
                     const float* __restrict__ W_ih,   // (512, 1)
                     const float* __restrict__ W_hh,   // (512, 128)
                     const float* __restrict__ b_ih,   // (512,)
                     const float* __restrict__ b_hh,   // (512,)
                     const float* __restrict__ W_lin,  // (1, 128)
                     const float* __restrict__ b_lin,  // (1,)
                     float*       __restrict__ out)    // (T, B, 1)
{
    const int tid   = threadIdx.x;
    const int batch = blockIdx.x;
    const int hsel  = tid & 1;       // 0: k in [0,64), 1: k in [64,128)
    const int r0    = tid & ~1;      // even row of this pair
    const int r1    = tid | 1;       // odd row of this pair

    // h split layout: h[k] at word k (k<64) or word k+16 (k>=64).
    __shared__ float h_lds[160];
    __shared__ float act[4 * HDIM];     // activated gates, index = row
    __shared__ float part[2];

    const float4* W4 = (const float4*)W_hh;   // row j = W4[j*32 ..]
    const float4* L4 = (const float4*)W_lin;  // 32 float4
    const int wbase0 = r0 * 32 + hsel * 16;
    const int wbase1 = r1 * 32 + hsel * 16;
    const int lbase  = hsel * 16;

    // ---- load W_hh rows into 32 named float4s ----
    #define DECL_W(i) float4 wa##i = W4[wbase0 + (i)]; float4 wb##i = W4[wbase1 + (i)];
    REP16(DECL_W)

    const float wihr0 = W_ih[r0];
    const float wihr1 = W_ih[r1];
    const float blin  = b_lin[0];
    const float wlin  = (tid < 2 * HDIM) ? W_lin[tid & (HDIM - 1)] : 0.0f;
    const float biasP0 = b_ih[r0] + b_hh[r0] + wihr0 * blin;
    const float biasP1 = b_ih[r1] + b_hh[r1] + wihr1 * blin;

    // ---- fold feedback: W' = W_hh + wih (x) W_lin ----
    #define FOLD_W(i) { float4 lv = L4[lbase + (i)]; \
        wa##i.x = fmaf(wihr0, lv.x, wa##i.x); wa##i.y = fmaf(wihr0, lv.y, wa##i.y); \
        wa##i.z = fmaf(wihr0, lv.z, wa##i.z); wa##i.w = fmaf(wihr0, lv.w, wa##i.w); \
        wb##i.x = fmaf(wihr1, lv.x, wb##i.x); wb##i.y = fmaf(wihr1, lv.y, wb##i.y); \
        wb##i.z = fmaf(wihr1, lv.z, wb##i.z); wb##i.w = fmaf(wihr1, lv.w, wb##i.w); }
    REP16(FOLD_W)

    // ---- pin: VOLATILE opaque defs ----
    #define PIN_W(i) asm volatile("" : "+v"(wa##i.x), "+v"(wa##i.y), "+v"(wa##i.z), "+v"(wa##i.w), \
                                       "+v"(wb##i.x), "+v"(wb##i.y), "+v"(wb##i.z), "+v"(wb##i.w));
    REP16(PIN_W)

    float c = 0.0f;
    const int hword = (tid & (HDIM - 1)) + ((tid & 64) ? 16 : 0);  // split addr
    if (tid < HDIM) h_lds[hword] = h0[label[batch] * HDIM + tid];
    __syncthreads();

    // y_init = h_init . W_lin + b_lin (for the t=0 bias correction)
    if (tid < HDIM) {
        float p = h_lds[hword] * wlin;
        #pragma unroll
        for (int off = 32; off > 0; off >>= 1) p += __shfl_xor(p, off, 64);
        if ((tid & 63) == 0) part[tid >> 6] = p;
    }
    __syncthreads();
    const float y0 = part[0] + part[1] + blin;

    float bb0 = biasP0 - wihr0 * y0;   // first-iteration bias (x_0 = 0)
    float bb1 = biasP1 - wihr1 * y0;

    const float4* hbase = (const float4*)(h_lds + hsel * 80);

    for (int t = 0; t < T_STEPS; ++t) {
        // write last step's y (part[] made visible by the closing barrier)
        if (tid == 0 && t > 0) out[(t - 1) * BATCH + batch] = part[0] + part[1] + blin;

        // ---------- Phase A: two half-row dots per thread ----------
        float a0 = hsel ? 0.0f : bb0;   // bias added once per row (even thread)
        float a1 = hsel ? 0.0f : bb1;
        float d0 = 0.0f, d1 = 0.0f;     // 4 independent FMA chains
        #define DOTP(i, j) { \
            float4 hv = hbase[(i)]; \
            float4 hw = hbase[(j)]; \
            a0 = fmaf(hv.x, wa##i.x, a0); a1 = fmaf(hv.x, wb##i.x, a1); \
            a0 = fmaf(hv.y, wa##i.y, a0); a1 = fmaf(hv.y, wb##i.y, a1); \
            a0 = fmaf(hv.z, wa##i.z, a0); a1 = fmaf(hv.z, wb##i.z, a1); \
            a0 = fmaf(hv.w, wa##i.w, a0); a1 = fmaf(hv.w, wb##i.w, a1); \
            d0 = fmaf(hw.x, wa##j.x, d0); d1 = fmaf(hw.x, wb##j.x, d1); \
            d0 = fmaf(hw.y, wa##j.y, d0); d1 = fmaf(hw.y, wb##j.y, d1); \
            d0 = fmaf(hw.z, wa##j.z, d0); d1 = fmaf(hw.z, wb##j.z, d1); \
            d0 = fmaf(hw.w, wa##j.w, d0); d1 = fmaf(hw.w, wb##j.w, d1); }
        DOTP(0, 1)  DOTP(2, 3)  DOTP(4, 5)  DOTP(6, 7)
        DOTP(8, 9)  DOTP(10, 11) DOTP(12, 13) DOTP(14, 15)

        float g0 = a0 + d0;                 // partial of row r0 (this half)
        float g1 = a1 + d1;                 // partial of row r1 (this half)
        g0 += __shfl_xor(g0, 1, 64);        // combine halves within the pair
        g1 += __shfl_xor(g1, 1, 64);
        const float pre = hsel ? g1 : g0;   // this thread's own row == tid

        // gate type by row block (wave-uniform: boundaries at 128-row marks)
        const int gt = tid >> 7;            // 0=i 1=f 2=g 3=o
        act[tid] = (gt == 2) ? tanh_f(pre) : sigmoid_f(pre);
        __syncthreads();

        // ---------- Phase B: waves 0-3 mirror the c/h update ----------
        if (tid < 2 * HDIM) {
            const int hh = tid & (HDIM - 1);
            const float iv = act[hh];
            const float fv = act[HDIM + hh];
            const float gv = act[2 * HDIM + hh];
            const float ov = act[3 * HDIM + hh];
            c = fmaf(fv, c, iv * gv);
            const float hn = ov * tanh_f(c);
            if (tid < HDIM) {
                h_lds[hword] = hn;          // waves 0-1: publish h
            } else {
                float p = hn * wlin;        // waves 2-3: y reduction
                #pragma unroll
                for (int off = 32; off > 0; off >>= 1) p += __shfl_xor(p, off, 64);
                if ((tid & 63) == 0) part[(tid - HDIM) >> 6] = p;
            }
        }
        __syncthreads();

        bb0 = biasP0;  bb1 = biasP1;        // drop t=0 correction after iter 0
    }

    if (tid == 0) out[(T_STEPS - 1) * BATCH + batch] = part[0] + part[1] + blin;
}

extern "C" void kernel_launch(void* const* d_in, const int* in_sizes, int n_in,
                              void* d_out, int out_size, void* d_ws, size_t ws_size,
                              hipStream_t stream) {
    // inputs: 0 input (unused), 1 label, 2 h0, 3 W_ih, 4 W_hh,
    //         5 b_ih, 6 b_hh, 7 W_lin, 8 b_lin
    const int*   label = (const int*)  d_in[1];
    const float* h0    = (const float*)d_in[2];
    const float* W_ih  = (const float*)d_in[3];
    const float* W_hh  = (const float*)d_in[4];
    const float* b_ih  = (const float*)d_in[5];
    const float* b_hh  = (const float*)d_in[6];
    const float* W_lin = (const float*)d_in[7];
    const float* b_lin = (const float*)d_in[8];
    float* out = (float*)d_out;

    lstm_seq_kernel<<<dim3(BATCH), dim3(512), 0, stream>>>(
        label, h0, W_ih, W_hh, b_ih, b_hh, W_lin, b_lin, out);
}

// Round 7
// 1979.943 us; speedup vs baseline: 1.0709x; 1.0709x over previous
//
#include <hip/hip_runtime.h>
#include <math.h>

// Problem constants: T=2048, B=256, H=128, IN_DIM=1, NUM_DATA=4096
#define T_STEPS 2048
#define BATCH   256
#define HDIM    128

__device__ __forceinline__ float fast_rcp(float x) { return __builtin_amdgcn_rcpf(x); }
__device__ __forceinline__ float sigmoid_f(float x) { return fast_rcp(1.0f + __expf(-x)); }
__device__ __forceinline__ float tanh_f(float x) {
    float e = __expf(2.0f * x);
    return 1.0f - 2.0f * fast_rcp(e + 1.0f);
}

#define REP8(M) M(0) M(1) M(2) M(3) M(4) M(5) M(6) M(7)

// R7: ONE barrier per step.
// Thread tid -> (element m = tid>>2, K-quarter q = tid&3). Each thread owns
// ALL FOUR gate rows of its element (i=m, f=m+128, g=m+256, o=m+384) over a
// 32-wide K slice (128 weights). After the 4x32 FMA block, shfl_xor(1) +
// shfl_xor(2) combine the 4 K-quarters -> every lane holds its element's 4
// full gates -> activation + c/h update are LOCAL (no act[] LDS exchange,
// no Phase B, no second barrier; c replicated x4 lanes, deterministic).
// h is double-buffered in LDS: iter t reads hbuf[cur], writes hbuf[cur^1].
// Wave 0 computes y_t from hbuf[cur] (race-free by dbuf) overlapped with
// its FMA stream, writes out[t-1]. Quarter bases padded to 36 words so the
// 4 distinct addresses of each ds_read_b128 hit disjoint bank groups.
// Feedback fold (absmax 0.0 in R3/R5): gates = h.(W_hh + W_ih (x) W_lin)^T
// + (b + W_ih*b_lin); t=0 corrected by -wih*y_init on iteration 0.
__global__ __launch_bounds__(512, 2)
void lstm_seq_kernel(const int*   __restrict__ label,
                     const float* __restrict__ h0,     // (1, 4096, 128)
                     const float* __restrict__ W_ih,   // (512, 1)
                     const float* __restrict__ W_hh,   // (512, 128)
                     const float* __restrict__ b_ih,   // (512,)
                     const float* __restrict__ b_hh,   // (512,)
                     const float* __restrict__ W_lin,  // (1, 128)
                     const float* __restrict__ b_lin,  // (1,)
                     float*       __restrict__ out)    // (T, B, 1)
{
    const int tid   = threadIdx.x;
    const int batch = blockIdx.x;
    const int m     = tid >> 2;     // h element 0..127
    const int q     = tid & 3;      // K-quarter 0..3
    const int q8    = q * 8;        // float4 index of K-slice start

    const int ri = m, rf = m + 128, rg = m + 256, ro = m + 384;

    // padded split: h[k] lives at word k + 4*(k>>5); quarter q base = 36q
    // words (144q bytes, 16B-aligned). Per-b128-inst the 4 quarter addresses
    // cover 4 disjoint 4-bank groups -> conflict-free broadcast.
    __shared__ float hbuf[2][160];

    const float4* W4 = (const float4*)W_hh;   // row j = W4[j*32 ..]
    const float4* L4 = (const float4*)W_lin;  // 32 float4

    // ---- load the 4 gate-row K-slices (8 float4 each) ----
    #define DECL_W(i) \
        float4 wi##i = W4[ri * 32 + q8 + (i)]; \
        float4 wf##i = W4[rf * 32 + q8 + (i)]; \
        float4 wg##i = W4[rg * 32 + q8 + (i)]; \
        float4 wo##i = W4[ro * 32 + q8 + (i)];
    REP8(DECL_W)

    const float wih_i = W_ih[ri], wih_f = W_ih[rf];
    const float wih_g = W_ih[rg], wih_o = W_ih[ro];
    const float blin  = b_lin[0];

    const float bi_ = b_ih[ri] + b_hh[ri] + wih_i * blin;
    const float bf_ = b_ih[rf] + b_hh[rf] + wih_f * blin;
    const float bg_ = b_ih[rg] + b_hh[rg] + wih_g * blin;
    const float bo_ = b_ih[ro] + b_hh[ro] + wih_o * blin;

    // ---- fold feedback: W' = W_hh + wih (x) W_lin ----
    #define FOLD_W(i) { float4 lv = L4[q8 + (i)]; \
        wi##i.x = fmaf(wih_i, lv.x, wi##i.x); wi##i.y = fmaf(wih_i, lv.y, wi##i.y); \
        wi##i.z = fmaf(wih_i, lv.z, wi##i.z); wi##i.w = fmaf(wih_i, lv.w, wi##i.w); \
        wf##i.x = fmaf(wih_f, lv.x, wf##i.x); wf##i.y = fmaf(wih_f, lv.y, wf##i.y); \
        wf##i.z = fmaf(wih_f, lv.z, wf##i.z); wf##i.w = fmaf(wih_f, lv.w, wf##i.w); \
        wg##i.x = fmaf(wih_g, lv.x, wg##i.x); wg##i.y = fmaf(wih_g, lv.y, wg##i.y); \
        wg##i.z = fmaf(wih_g, lv.z, wg##i.z); wg##i.w = fmaf(wih_g, lv.w, wg##i.w); \
        wo##i.x = fmaf(wih_o, lv.x, wo##i.x); wo##i.y = fmaf(wih_o, lv.y, wo##i.y); \
        wo##i.z = fmaf(wih_o, lv.z, wo##i.z); wo##i.w = fmaf(wih_o, lv.w, wo##i.w); }
    REP8(FOLD_W)

    // ---- volatile pins: no remat / no sinking of the weight loads ----
    #define PIN_W(i) asm volatile("" : \
        "+v"(wi##i.x), "+v"(wi##i.y), "+v"(wi##i.z), "+v"(wi##i.w), \
        "+v"(wf##i.x), "+v"(wf##i.y), "+v"(wf##i.z), "+v"(wf##i.w), \
        "+v"(wg##i.x), "+v"(wg##i.y), "+v"(wg##i.z), "+v"(wg##i.w), \
        "+v"(wo##i.x), "+v"(wo##i.y), "+v"(wo##i.z), "+v"(wo##i.w));
    REP8(PIN_W)

    // y-dot lane constants (wave 0 uses them per step; all compute them)
    const int   lane = tid & 63;
    const int   ya0  = lane + ((lane >> 5) << 2);   // word of h[lane]
    const int   ya1  = ya0 + 72;                    // word of h[lane+64]
    const float wl_a = W_lin[lane];
    const float wl_b = W_lin[lane + 64];

    // ---- init h ----
    if (tid < HDIM) hbuf[0][tid + ((tid >> 5) << 2)] = h0[label[batch] * HDIM + tid];
    __syncthreads();

    // y_init: every wave butterflies over the same data -> uniform result
    float p0 = hbuf[0][ya0] * wl_a + hbuf[0][ya1] * wl_b;
    #pragma unroll
    for (int off = 1; off < 64; off <<= 1) p0 += __shfl_xor(p0, off, 64);
    const float y0 = p0 + blin;

    // iteration-0 biases carry the x_0 = 0 correction
    float cbi = bi_ - wih_i * y0;
    float cbf = bf_ - wih_f * y0;
    float cbg = bg_ - wih_g * y0;
    float cbo = bo_ - wih_o * y0;

    float c   = 0.0f;
    int   cur = 0;

    for (int t = 0; t < T_STEPS; ++t) {
        float* hb = hbuf[cur];

        // ---- deferred y of the CURRENT h (wave 0; overlaps FMA stream) ----
        float yv = 0.0f;
        if (tid < 64) {
            yv = hb[ya0] * wl_a + hb[ya1] * wl_b;
            #pragma unroll
            for (int off = 1; off < 64; off <<= 1) yv += __shfl_xor(yv, off, 64);
            if (tid == 0 && t > 0) out[(t - 1) * BATCH + batch] = yv + blin;
        }

        // ---- 4 gate dots over this thread's K-quarter (32 FMAs each) ----
        const float4* hq = (const float4*)(hb + 36 * q);
        float ai = 0.f, af = 0.f, ag = 0.f, ao = 0.f;
        #define DOT4(i) { float4 hv = hq[(i)]; \
            ai = fmaf(hv.x, wi##i.x, ai); ai = fmaf(hv.y, wi##i.y, ai); \
            ai = fmaf(hv.z, wi##i.z, ai); ai = fmaf(hv.w, wi##i.w, ai); \
            af = fmaf(hv.x, wf##i.x, af); af = fmaf(hv.y, wf##i.y, af); \
            af = fmaf(hv.z, wf##i.z, af); af = fmaf(hv.w, wf##i.w, af); \
            ag = fmaf(hv.x, wg##i.x, ag); ag = fmaf(hv.y, wg##i.y, ag); \
            ag = fmaf(hv.z, wg##i.z, ag); ag = fmaf(hv.w, wg##i.w, ag); \
            ao = fmaf(hv.x, wo##i.x, ao); ao = fmaf(hv.y, wo##i.y, ao); \
            ao = fmaf(hv.z, wo##i.z, ao); ao = fmaf(hv.w, wo##i.w, ao); }
        REP8(DOT4)

        // ---- combine the 4 K-quarters (2-level butterfly in the 4-group) ----
        ai += __shfl_xor(ai, 1, 64); af += __shfl_xor(af, 1, 64);
        ag += __shfl_xor(ag, 1, 64); ao += __shfl_xor(ao, 1, 64);
        ai += __shfl_xor(ai, 2, 64); af += __shfl_xor(af, 2, 64);
        ag += __shfl_xor(ag, 2, 64); ao += __shfl_xor(ao, 2, 64);

        // ---- local activation + c/h update (replicated x4 lanes) ----
        const float iv = sigmoid_f(ai + cbi);
        const float fv = sigmoid_f(af + cbf);
        const float gv = tanh_f  (ag + cbg);
        const float ov = sigmoid_f(ao + cbo);
        c = fmaf(fv, c, iv * gv);
        const float hn = ov * tanh_f(c);
        if ((tid & 3) == 0) hbuf[cur ^ 1][m + ((m >> 5) << 2)] = hn;

        __syncthreads();          // the ONE barrier per step
        cur ^= 1;
        cbi = bi_; cbf = bf_; cbg = bg_; cbo = bo_;   // drop t=0 correction
    }

    // final y from h_T
    if (tid < 64) {
        float yv = hbuf[cur][ya0] * wl_a + hbuf[cur][ya1] * wl_b;
        #pragma unroll
        for (int off = 1; off < 64; off <<= 1) yv += __shfl_xor(yv, off, 64);
        if (tid == 0) out[(T_STEPS - 1) * BATCH + batch] = yv + blin;
    }
}

extern "C" void kernel_launch(void* const* d_in, const int* in_sizes, int n_in,
                              void* d_out, int out_size, void* d_ws, size_t ws_size,
                              hipStream_t stream) {
    // inputs: 0 input (unused), 1 label, 2 h0, 3 W_ih, 4 W_hh,
    //         5 b_ih, 6 b_hh, 7 W_lin, 8 b_lin
    const int*   label = (const int*)  d_in[1];
    const float* h0    = (const float*)d_in[2];
    const float* W_ih  = (const float*)d_in[3];
    const float* W_hh  = (const float*)d_in[4];
    const float* b_ih  = (const float*)d_in[5];
    const float* b_hh  = (const float*)d_in[6];
    const float* W_lin = (const float*)d_in[7];
    const float* b_lin = (const float*)d_in[8];
    float* out = (float*)d_out;

    lstm_seq_kernel<<<dim3(BATCH), dim3(512), 0, stream>>>(
        label, h0, W_ih, W_hh, b_ih, b_hh, W_lin, b_lin, out);
}

// Round 8
// 1958.652 us; speedup vs baseline: 1.0826x; 1.0109x over previous
//
#include <hip/hip_runtime.h>
#include <math.h>

// Problem constants: T=2048, B=256, H=128, IN_DIM=1, NUM_DATA=4096
#define T_STEPS 2048
#define BATCH   256
#define HDIM    128

__device__ __forceinline__ float fast_rcp(float x) { return __builtin_amdgcn_rcpf(x); }
__device__ __forceinline__ float sigmoid_f(float x) { return fast_rcp(1.0f + __expf(-x)); }
__device__ __forceinline__ float tanh_f(float x) {
    float e = __expf(2.0f * x);
    return 1.0f - 2.0f * fast_rcp(e + 1.0f);
}

#define REP4(M) M(0) M(1) M(2) M(3)

// R8: 1024 threads/block, 64 weight floats per thread.
// R5-R7 evidence: allocator caps arch VGPRs ~84 and AGPR-parks the rest,
// charging one v_accvgpr_read per weight use (R7: ~1460 VALU cyc/step vs
// ~680 source-level). Shrinking the per-thread weight set from 128 to 64
// floats brings total need (~100) near the cap, collapsing the tax.
// Thread tid -> (element m = tid>>3, K-eighth e = tid&7). Each thread owns
// all 4 gate rows of its element (i=m, f=m+128, g=m+256, o=m+384) over a
// 16-wide K slice. 3-level shfl_xor(1,2,4) combines the 8 K-slices ->
// every lane holds its element's 4 gates -> local activation + c/h update
// (replicated x8), ONE barrier/step. h double-buffered in LDS.
// h layout: eighth e at word base 20e (padded 16->20) so the 8 distinct
// broadcast addresses per ds_read_b128 land on disjoint 4-bank groups
// covering all 32 banks: (20e+4i) mod 32 = {0,20,8,28,16,4,24,12}+4i.
// Feedback fold (absmax 0.0 since R3): gates = h.(W_hh + W_ih (x) W_lin)^T
// + (b + W_ih*b_lin); t=0 corrected by -wih*y_init on iteration 0.
__global__ __launch_bounds__(1024, 4)
void lstm_seq_kernel(const int*   __restrict__ label,
                     const float* __restrict__ h0,     // (1, 4096, 128)
                     const float* __restrict__ W_ih,   // (512, 1)
                     const float* __restrict__ W_hh,   // (512, 128)
                     const float* __restrict__ b_ih,   // (512,)
                     const float* __restrict__ b_hh,   // (512,)
                     const float* __restrict__ W_lin,  // (1, 128)
                     const float* __restrict__ b_lin,  // (1,)
                     float*       __restrict__ out)    // (T, B, 1)
{
    const int tid   = threadIdx.x;
    const int batch = blockIdx.x;
    const int m     = tid >> 3;     // h element 0..127
    const int e     = tid & 7;      // K-eighth 0..7
    const int e4    = e * 4;        // float4 index of K-slice start

    const int ri = m, rf = m + 128, rg = m + 256, ro = m + 384;

    __shared__ float hbuf[2][160];  // 8 eighths x 20 words, double-buffered

    const float4* W4 = (const float4*)W_hh;   // row j = W4[j*32 ..]
    const float4* L4 = (const float4*)W_lin;  // 32 float4

    // ---- load the 4 gate-row K-slices (4 float4 each = 64 floats) ----
    #define DECL_W(i) \
        float4 wi##i = W4[ri * 32 + e4 + (i)]; \
        float4 wf##i = W4[rf * 32 + e4 + (i)]; \
        float4 wg##i = W4[rg * 32 + e4 + (i)]; \
        float4 wo##i = W4[ro * 32 + e4 + (i)];
    REP4(DECL_W)

    const float wih_i = W_ih[ri], wih_f = W_ih[rf];
    const float wih_g = W_ih[rg], wih_o = W_ih[ro];
    const float blin  = b_lin[0];

    const float bi_ = b_ih[ri] + b_hh[ri] + wih_i * blin;
    const float bf_ = b_ih[rf] + b_hh[rf] + wih_f * blin;
    const float bg_ = b_ih[rg] + b_hh[rg] + wih_g * blin;
    const float bo_ = b_ih[ro] + b_hh[ro] + wih_o * blin;

    // ---- fold feedback: W' = W_hh + wih (x) W_lin ----
    #define FOLD_W(i) { float4 lv = L4[e4 + (i)]; \
        wi##i.x = fmaf(wih_i, lv.x, wi##i.x); wi##i.y = fmaf(wih_i, lv.y, wi##i.y); \
        wi##i.z = fmaf(wih_i, lv.z, wi##i.z); wi##i.w = fmaf(wih_i, lv.w, wi##i.w); \
        wf##i.x = fmaf(wih_f, lv.x, wf##i.x); wf##i.y = fmaf(wih_f, lv.y, wf##i.y); \
        wf##i.z = fmaf(wih_f, lv.z, wf##i.z); wf##i.w = fmaf(wih_f, lv.w, wf##i.w); \
        wg##i.x = fmaf(wih_g, lv.x, wg##i.x); wg##i.y = fmaf(wih_g, lv.y, wg##i.y); \
        wg##i.z = fmaf(wih_g, lv.z, wg##i.z); wg##i.w = fmaf(wih_g, lv.w, wg##i.w); \
        wo##i.x = fmaf(wih_o, lv.x, wo##i.x); wo##i.y = fmaf(wih_o, lv.y, wo##i.y); \
        wo##i.z = fmaf(wih_o, lv.z, wo##i.z); wo##i.w = fmaf(wih_o, lv.w, wo##i.w); }
    REP4(FOLD_W)

    // ---- volatile pins: no remat / no sinking of the weight loads ----
    #define PIN_W(i) asm volatile("" : \
        "+v"(wi##i.x), "+v"(wi##i.y), "+v"(wi##i.z), "+v"(wi##i.w), \
        "+v"(wf##i.x), "+v"(wf##i.y), "+v"(wf##i.z), "+v"(wf##i.w), \
        "+v"(wg##i.x), "+v"(wg##i.y), "+v"(wg##i.z), "+v"(wg##i.w), \
        "+v"(wo##i.x), "+v"(wo##i.y), "+v"(wo##i.z), "+v"(wo##i.w));
    REP4(PIN_W)

    // y-dot lane constants (wave 0 uses them per step)
    const int   lane = tid & 63;
    const int   ya0  = 20 * (lane >> 4) + (lane & 15);   // word of h[lane]
    const int   ya1  = ya0 + 80;                          // word of h[lane+64]
    const float wl_a = W_lin[lane];
    const float wl_b = W_lin[lane + 64];

    // ---- init h ----
    if (tid < HDIM) hbuf[0][20 * (tid >> 4) + (tid & 15)] = h0[label[batch] * HDIM + tid];
    __syncthreads();

    // y_init: every wave butterflies over the same data -> uniform result
    float p0 = hbuf[0][ya0] * wl_a + hbuf[0][ya1] * wl_b;
    #pragma unroll
    for (int off = 1; off < 64; off <<= 1) p0 += __shfl_xor(p0, off, 64);
    const float y0 = p0 + blin;

    // iteration-0 biases carry the x_0 = 0 correction
    float cbi = bi_ - wih_i * y0;
    float cbf = bf_ - wih_f * y0;
    float cbg = bg_ - wih_g * y0;
    float cbo = bo_ - wih_o * y0;

    float c   = 0.0f;
    int   cur = 0;

    for (int t = 0; t < T_STEPS; ++t) {
        float* hb = hbuf[cur];

        // ---- deferred y of the CURRENT h (wave 0; overlaps FMA stream) ----
        if (tid < 64) {
            float yv = hb[ya0] * wl_a + hb[ya1] * wl_b;
            #pragma unroll
            for (int off = 1; off < 64; off <<= 1) yv += __shfl_xor(yv, off, 64);
            if (tid == 0 && t > 0) out[(t - 1) * BATCH + batch] = yv + blin;
        }

        // ---- 4 gate dots over this thread's K-eighth (16 FMAs each) ----
        const float4* hq = (const float4*)(hb + 20 * e);
        float ai = 0.f, af = 0.f, ag = 0.f, ao = 0.f;
        #define DOT4(i) { float4 hv = hq[(i)]; \
            ai = fmaf(hv.x, wi##i.x, ai); ai = fmaf(hv.y, wi##i.y, ai); \
            ai = fmaf(hv.z, wi##i.z, ai); ai = fmaf(hv.w, wi##i.w, ai); \
            af = fmaf(hv.x, wf##i.x, af); af = fmaf(hv.y, wf##i.y, af); \
            af = fmaf(hv.z, wf##i.z, af); af = fmaf(hv.w, wf##i.w, af); \
            ag = fmaf(hv.x, wg##i.x, ag); ag = fmaf(hv.y, wg##i.y, ag); \
            ag = fmaf(hv.z, wg##i.z, ag); ag = fmaf(hv.w, wg##i.w, ag); \
            ao = fmaf(hv.x, wo##i.x, ao); ao = fmaf(hv.y, wo##i.y, ao); \
            ao = fmaf(hv.z, wo##i.z, ao); ao = fmaf(hv.w, wo##i.w, ao); }
        REP4(DOT4)

        // ---- combine the 8 K-eighths (3-level butterfly in the 8-group) ----
        ai += __shfl_xor(ai, 1, 64); af += __shfl_xor(af, 1, 64);
        ag += __shfl_xor(ag, 1, 64); ao += __shfl_xor(ao, 1, 64);
        ai += __shfl_xor(ai, 2, 64); af += __shfl_xor(af, 2, 64);
        ag += __shfl_xor(ag, 2, 64); ao += __shfl_xor(ao, 2, 64);
        ai += __shfl_xor(ai, 4, 64); af += __shfl_xor(af, 4, 64);
        ag += __shfl_xor(ag, 4, 64); ao += __shfl_xor(ao, 4, 64);

        // ---- local activation + c/h update (replicated x8 lanes) ----
        const float iv = sigmoid_f(ai + cbi);
        const float fv = sigmoid_f(af + cbf);
        const float gv = tanh_f  (ag + cbg);
        const float ov = sigmoid_f(ao + cbo);
        c = fmaf(fv, c, iv * gv);
        const float hn = ov * tanh_f(c);
        if (e == 0) hbuf[cur ^ 1][20 * (m >> 4) + (m & 15)] = hn;

        __syncthreads();          // the ONE barrier per step
        cur ^= 1;
        cbi = bi_; cbf = bf_; cbg = bg_; cbo = bo_;   // drop t=0 correction
    }

    // final y from h_T
    if (tid < 64) {
        float yv = hbuf[cur][ya0] * wl_a + hbuf[cur][ya1] * wl_b;
        #pragma unroll
        for (int off = 1; off < 64; off <<= 1) yv += __shfl_xor(yv, off, 64);
        if (tid == 0) out[(T_STEPS - 1) * BATCH + batch] = yv + blin;
    }
}

extern "C" void kernel_launch(void* const* d_in, const int* in_sizes, int n_in,
                              void* d_out, int out_size, void* d_ws, size_t ws_size,
                              hipStream_t stream) {
    // inputs: 0 input (unused), 1 label, 2 h0, 3 W_ih, 4 W_hh,
    //         5 b_ih, 6 b_hh, 7 W_lin, 8 b_lin
    const int*   label = (const int*)  d_in[1];
    const float* h0    = (const float*)d_in[2];
    const float* W_ih  = (const float*)d_in[3];
    const float* W_hh  = (const float*)d_in[4];
    const float* b_ih  = (const float*)d_in[5];
    const float* b_hh  = (const float*)d_in[6];
    const float* W_lin = (const float*)d_in[7];
    const float* b_lin = (const float*)d_in[8];
    float* out = (float*)d_out;

    lstm_seq_kernel<<<dim3(BATCH), dim3(1024), 0, stream>>>(
        label, h0, W_ih, W_hh, b_ih, b_hh, W_lin, b_lin, out);
}

// Round 10
// 1679.975 us; speedup vs baseline: 1.2621x; 1.1659x over previous
//
#include <hip/hip_runtime.h>
#include <math.h>

// Problem constants: T=2048, B=256, H=128, IN_DIM=1, NUM_DATA=4096
#define T_STEPS 2048
#define BATCH   256
#define HDIM    128

__device__ __forceinline__ float fast_rcp(float x) { return __builtin_amdgcn_rcpf(x); }
__device__ __forceinline__ float sigmoid_f(float x) { return fast_rcp(1.0f + __expf(-x)); }
__device__ __forceinline__ float tanh_f(float x) {
    float e = __expf(2.0f * x);
    return 1.0f - 2.0f * fast_rcp(e + 1.0f);
}

#define REP8(M) M(0) M(1) M(2) M(3) M(4) M(5) M(6) M(7)

// R10: IN-LOOP volatile pins force the 128 weight floats to be ARCH-VGPR,
// LOOP-CARRIED values.
// Chain of evidence: R2-R8 all ~2ms, VALU-issue-bound at ~2.5x source inst
// count with VGPR_Count 52-84 (weights AGPR-parked, +1 v_accvgpr_read per
// use). R9 proved v_fma_f32 cannot source AGPRs (compile error). Out-of-
// loop pins only force v-residency at the pin site; the allocator re-parks
// loop-invariant values in AGPRs afterwards. Redefining the weights via
// empty volatile asm EVERY ITERATION makes them loop-carried phi nodes:
// AGPR-parking would cost a read+write pair per iteration, so the cost
// model should keep them in arch VGPRs and feed v_fma directly.
//
// Structure = R7 (verified absmax 0.0, SQ_LDS_BANK_CONFLICT == 0):
// 512 threads (2 waves/EU -> 256-VGPR budget; need ~180), thread ->
// (element m = tid>>2, K-quarter q = tid&3), all 4 gate rows per thread
// over a 32-wide K slice; shfl_xor(1,2) combines quarters; local
// activation + c/h update (replicated x4); h double-buffered in LDS with
// 36-word quarter bases; ONE barrier/step; wave-0 y-dot overlapped,
// out[] written one step deferred.
// Feedback fold: gates = h.(W_hh + W_ih (x) W_lin)^T + (b + W_ih*b_lin);
// t=0 corrected by -wih*y_init on iteration 0.
__global__ __launch_bounds__(512, 2)
void lstm_seq_kernel(const int*   __restrict__ label,
                     const float* __restrict__ h0,     // (1, 4096, 128)
                     const float* __restrict__ W_ih,   // (512, 1)
                     const float* __restrict__ W_hh,   // (512, 128)
                     const float* __restrict__ b_ih,   // (512,)
                     const float* __restrict__ b_hh,   // (512,)
                     const float* __restrict__ W_lin,  // (1, 128)
                     const float* __restrict__ b_lin,  // (1,)
                     float*       __restrict__ out)    // (T, B, 1)
{
    const int tid   = threadIdx.x;
    const int batch = blockIdx.x;
    const int m     = tid >> 2;     // h element 0..127
    const int q     = tid & 3;      // K-quarter 0..3
    const int q8    = q * 8;        // float4 index of K-slice start

    const int ri = m, rf = m + 128, rg = m + 256, ro = m + 384;

    __shared__ float hbuf[2][160];  // quarters at 36q words (conflict-free)

    const float4* W4 = (const float4*)W_hh;   // row j = W4[j*32 ..]
    const float4* L4 = (const float4*)W_lin;  // 32 float4

    // ---- load the 4 gate-row K-slices (8 float4 each = 128 floats) ----
    #define DECL_W(i) \
        float4 wi##i = W4[ri * 32 + q8 + (i)]; \
        float4 wf##i = W4[rf * 32 + q8 + (i)]; \
        float4 wg##i = W4[rg * 32 + q8 + (i)]; \
        float4 wo##i = W4[ro * 32 + q8 + (i)];
    REP8(DECL_W)

    const float wih_i = W_ih[ri], wih_f = W_ih[rf];
    const float wih_g = W_ih[rg], wih_o = W_ih[ro];
    const float blin  = b_lin[0];

    const float bi_ = b_ih[ri] + b_hh[ri] + wih_i * blin;
    const float bf_ = b_ih[rf] + b_hh[rf] + wih_f * blin;
    const float bg_ = b_ih[rg] + b_hh[rg] + wih_g * blin;
    const float bo_ = b_ih[ro] + b_hh[ro] + wih_o * blin;

    // ---- fold feedback: W' = W_hh + wih (x) W_lin ----
    #define FOLD_W(i) { float4 lv = L4[q8 + (i)]; \
        wi##i.x = fmaf(wih_i, lv.x, wi##i.x); wi##i.y = fmaf(wih_i, lv.y, wi##i.y); \
        wi##i.z = fmaf(wih_i, lv.z, wi##i.z); wi##i.w = fmaf(wih_i, lv.w, wi##i.w); \
        wf##i.x = fmaf(wih_f, lv.x, wf##i.x); wf##i.y = fmaf(wih_f, lv.y, wf##i.y); \
        wf##i.z = fmaf(wih_f, lv.z, wf##i.z); wf##i.w = fmaf(wih_f, lv.w, wf##i.w); \
        wg##i.x = fmaf(wih_g, lv.x, wg##i.x); wg##i.y = fmaf(wih_g, lv.y, wg##i.y); \
        wg##i.z = fmaf(wih_g, lv.z, wg##i.z); wg##i.w = fmaf(wih_g, lv.w, wg##i.w); \
        wo##i.x = fmaf(wih_o, lv.x, wo##i.x); wo##i.y = fmaf(wih_o, lv.y, wo##i.y); \
        wo##i.z = fmaf(wih_o, lv.z, wo##i.z); wo##i.w = fmaf(wih_o, lv.w, wo##i.w); }
    REP8(FOLD_W)

    // in-loop pin: redefines all 16 components of group i (volatile, empty)
    #define PIN_W(i) asm volatile("" : \
        "+v"(wi##i.x), "+v"(wi##i.y), "+v"(wi##i.z), "+v"(wi##i.w), \
        "+v"(wf##i.x), "+v"(wf##i.y), "+v"(wf##i.z), "+v"(wf##i.w), \
        "+v"(wg##i.x), "+v"(wg##i.y), "+v"(wg##i.z), "+v"(wg##i.w), \
        "+v"(wo##i.x), "+v"(wo##i.y), "+v"(wo##i.z), "+v"(wo##i.w));

    // y-dot lane constants (wave 0 uses them per step)
    const int   lane = tid & 63;
    const int   ya0  = lane + ((lane >> 5) << 2);   // word of h[lane]
    const int   ya1  = ya0 + 72;                    // word of h[lane+64]
    const float wl_a = W_lin[lane];
    const float wl_b = W_lin[lane + 64];

    // ---- init h ----
    if (tid < HDIM) hbuf[0][tid + ((tid >> 5) << 2)] = h0[label[batch] * HDIM + tid];
    __syncthreads();

    // y_init (uniform across waves)
    float p0 = hbuf[0][ya0] * wl_a + hbuf[0][ya1] * wl_b;
    #pragma unroll
    for (int off = 1; off < 64; off <<= 1) p0 += __shfl_xor(p0, off, 64);
    const float y0 = p0 + blin;

    // iteration-0 biases carry the x_0 = 0 correction
    float cbi = bi_ - wih_i * y0;
    float cbf = bf_ - wih_f * y0;
    float cbg = bg_ - wih_g * y0;
    float cbo = bo_ - wih_o * y0;

    float c   = 0.0f;
    int   cur = 0;

    for (int t = 0; t < T_STEPS; ++t) {
        float* hb = hbuf[cur];

        // ---- THE PINS: every iteration, weights are (opaquely) redefined
        // -> loop-carried arch-VGPR values; AGPR-parking now costs a
        // read+write pair per iter, so the allocator should keep them in v.
        REP8(PIN_W)

        // ---- deferred y of the CURRENT h (wave 0; overlaps FMA stream) ----
        if (tid < 64) {
            float yv = hb[ya0] * wl_a + hb[ya1] * wl_b;
            #pragma unroll
            for (int off = 1; off < 64; off <<= 1) yv += __shfl_xor(yv, off, 64);
            if (tid == 0 && t > 0) out[(t - 1) * BATCH + batch] = yv + blin;
        }

        // ---- 4 gate dots over this thread's K-quarter (32 FMAs each) ----
        const float4* hq = (const float4*)(hb + 36 * q);
        float ai = 0.f, af = 0.f, ag = 0.f, ao = 0.f;
        #define DOT4(i) { float4 hv = hq[(i)]; \
            ai = fmaf(hv.x, wi##i.x, ai); ai = fmaf(hv.y, wi##i.y, ai); \
            ai = fmaf(hv.z, wi##i.z, ai); ai = fmaf(hv.w, wi##i.w, ai); \
            af = fmaf(hv.x, wf##i.x, af); af = fmaf(hv.y, wf##i.y, af); \
            af = fmaf(hv.z, wf##i.z, af); af = fmaf(hv.w, wf##i.w, af); \
            ag = fmaf(hv.x, wg##i.x, ag); ag = fmaf(hv.y, wg##i.y, ag); \
            ag = fmaf(hv.z, wg##i.z, ag); ag = fmaf(hv.w, wg##i.w, ag); \
            ao = fmaf(hv.x, wo##i.x, ao); ao = fmaf(hv.y, wo##i.y, ao); \
            ao = fmaf(hv.z, wo##i.z, ao); ao = fmaf(hv.w, wo##i.w, ao); }
        REP8(DOT4)

        // ---- combine the 4 K-quarters ----
        ai += __shfl_xor(ai, 1, 64); af += __shfl_xor(af, 1, 64);
        ag += __shfl_xor(ag, 1, 64); ao += __shfl_xor(ao, 1, 64);
        ai += __shfl_xor(ai, 2, 64); af += __shfl_xor(af, 2, 64);
        ag += __shfl_xor(ag, 2, 64); ao += __shfl_xor(ao, 2, 64);

        // ---- local activation + c/h update (replicated x4 lanes) ----
        const float iv = sigmoid_f(ai + cbi);
        const float fv = sigmoid_f(af + cbf);
        const float gv = tanh_f  (ag + cbg);
        const float ov = sigmoid_f(ao + cbo);
        c = fmaf(fv, c, iv * gv);
        const float hn = ov * tanh_f(c);
        if (q == 0) hbuf[cur ^ 1][m + ((m >> 5) << 2)] = hn;

        __syncthreads();          // the ONE barrier per step
        cur ^= 1;
        cbi = bi_; cbf = bf_; cbg = bg_; cbo = bo_;   // drop t=0 correction
    }

    // final y from h_T
    if (tid < 64) {
        float yv = hbuf[cur][ya0] * wl_a + hbuf[cur][ya1] * wl_b;
        #pragma unroll
        for (int off = 1; off < 64; off <<= 1) yv += __shfl_xor(yv, off, 64);
        if (tid == 0) out[(T_STEPS - 1) * BATCH + batch] = yv + blin;
    }
}

extern "C" void kernel_launch(void* const* d_in, const int* in_sizes, int n_in,
                              void* d_out, int out_size, void* d_ws, size_t ws_size,
                              hipStream_t stream) {
    // inputs: 0 input (unused), 1 label, 2 h0, 3 W_ih, 4 W_hh,
    //         5 b_ih, 6 b_hh, 7 W_lin, 8 b_lin
    const int*   label = (const int*)  d_in[1];
    const float* h0    = (const float*)d_in[2];
    const float* W_ih  = (const float*)d_in[3];
    const float* W_hh  = (const float*)d_in[4];
    const float* b_ih  = (const float*)d_in[5];
    const float* b_hh  = (const float*)d_in[6];
    const float* W_lin = (const float*)d_in[7];
    const float* b_lin = (const float*)d_in[8];
    float* out = (float*)d_out;

    lstm_seq_kernel<<<dim3(BATCH), dim3(512), 0, stream>>>(
        label, h0, W_ih, W_hh, b_ih, b_hh, W_lin, b_lin, out);
}